// Round 11
// baseline (286.048 us; speedup 1.0000x reference)
//
#include <hip/hip_runtime.h>

// Problem constants (from reference): E=1024, H=16, D=64, B=32, S=1024.
// ALGEBRA: softmax over a length-1 key axis == 1.0 exactly, so attention
// collapses: attn_out[b,:] = Wo @ (Wv @ (W_heat @ heat[b] + b_heat) + bv) + bo
// (independent of s; the img projection / Q / K path is dead code).
// Final: out[b,s,:] = LayerNorm(img_feat[b,s,:] + a[b,:]) * gamma + beta.
// All tensors fp32.
//
// Ledger: r10 (r4-body + NT load/store) = 278.9 total, BEST; NT-load was
// the first real LN win (~-11 us) -> L3-bypass / clean-read-stream theory
// confirmed. In the NT regime every img load is a uniform HBM miss, so the
// limiter becomes memory-level parallelism. r10's rotation keeps only 2
// rows (8 KiB) in flight per wave. This round: the r7 max-MLP layout
// (4 rows/wave, 16 lanes/row, ALL 16 KB of loads issued as one batch
// before any dependent op, VGPR ~52, grid 2048) + NT load/store.
// Single-variable change vs r7 (add NT) and vs r10 (layout swap).
// Pre-commit: neutral vs 278.9 => LN at machine ceiling, declare roofline.

#define E_DIM 1024
#define B_DIM 32
#define S_DIM 1024

typedef float nvf4 __attribute__((ext_vector_type(4)));  // NT-builtin-legal

// ---- GEMV stage: y[b,e] = dot(W[e,:], x[b,:]) + bias[e] -------------------
// (unchanged from the passing round-3..10 version)
__global__ __launch_bounds__(256) void gemv_xlds(
        const float* __restrict__ W,    // [E,E] row-major
        const float* __restrict__ bias, // [E]
        const float* __restrict__ x,    // [B,E]
        float* __restrict__ y) {        // [B,E]
    __shared__ float4 xs[8 * 256];       // 8 batches x 1024 f32 = 32 KiB
    const int t = threadIdx.x;
    const int rg = blockIdx.x & 255;     // row group -> rows [rg*4, rg*4+4)
    const int bq = blockIdx.x >> 8;      // batch quarter -> batches [bq*8, ..+8)

    const float4* x4 = reinterpret_cast<const float4*>(x) + (size_t)bq * 8 * 256;
    #pragma unroll
    for (int i = 0; i < 8; ++i)
        xs[i * 256 + t] = x4[i * 256 + t];
    __syncthreads();

    const int wave = t >> 6;
    const int lane = t & 63;
    const int e = rg * 4 + wave;

    const float4* w4 = reinterpret_cast<const float4*>(W + (size_t)e * E_DIM);
    float4 w0 = w4[lane];
    float4 w1 = w4[64 + lane];
    float4 w2 = w4[128 + lane];
    float4 w3 = w4[192 + lane];

    float acc[8];
    #pragma unroll
    for (int i = 0; i < 8; ++i) acc[i] = 0.f;

    #pragma unroll
    for (int i = 0; i < 8; ++i) {
        float4 a0 = xs[i * 256 + lane];
        float4 a1 = xs[i * 256 + 64 + lane];
        float4 a2 = xs[i * 256 + 128 + lane];
        float4 a3 = xs[i * 256 + 192 + lane];
        float r = w0.x * a0.x + w0.y * a0.y + w0.z * a0.z + w0.w * a0.w;
        r += w1.x * a1.x + w1.y * a1.y + w1.z * a1.z + w1.w * a1.w;
        r += w2.x * a2.x + w2.y * a2.y + w2.z * a2.z + w2.w * a2.w;
        r += w3.x * a3.x + w3.y * a3.y + w3.z * a3.z + w3.w * a3.w;
        acc[i] = r;
    }

    #pragma unroll
    for (int off = 32; off; off >>= 1) {
        #pragma unroll
        for (int i = 0; i < 8; ++i)
            acc[i] += __shfl_xor(acc[i], off, 64);
    }

    if (lane == 0) {
        const float bs = bias[e];
        #pragma unroll
        for (int i = 0; i < 8; ++i)
            y[(size_t)(bq * 8 + i) * E_DIM + e] = acc[i] + bs;
    }
}

// ---- Fused residual-add + LayerNorm: max-MLP layout + NT streams -----------
// Wave handles 4 consecutive rows side by side: lane group g = lane>>4 owns
// row row0+g; lane's f4 slots are (lane&15) + 16*p. All 16 loads (16 KB per
// wave) issue as ONE batch of independent NT loads before any dependent
// arithmetic (fence pins the batch). Reduce = 4-stride butterfly within
// 16-lane groups. gamma/beta/a loaded per-slot from hot cache (keeps VGPR
// ~52 -> high wave residency). Stores NT (out never read).
__global__ __launch_bounds__(256) void resid_ln(
        const float* __restrict__ img,   // [B,S,E]
        const float* __restrict__ a,     // [B,E]
        const float* __restrict__ gamma, // [E]
        const float* __restrict__ beta,  // [E]
        float* __restrict__ out) {       // [B,S,E]
    const int t = threadIdx.x;
    const int wave = t >> 6;
    const int lane = t & 63;
    const int m = lane & 15;                        // lane within row group
    const int row = blockIdx.x * 16 + wave * 4 + (lane >> 4);
    const int b = row >> 10;                        // 16 | 1024: no straddle

    const nvf4* i4 = reinterpret_cast<const nvf4*>(img) + (size_t)row * 256;
    const float4* a4 = reinterpret_cast<const float4*>(a) + (size_t)b * 256;
    const float4* g4 = reinterpret_cast<const float4*>(gamma);
    const float4* b4 = reinterpret_cast<const float4*>(beta);
    nvf4* o4 = reinterpret_cast<nvf4*>(out) + (size_t)row * 256;

    // Phase A: one unbroken batch of 16 independent NT loads (16 KB/wave in
    // flight before any dependent arithmetic). Fence pins the batch.
    nvf4 y[16];
    #pragma unroll
    for (int p = 0; p < 16; ++p)
        y[p] = __builtin_nontemporal_load(&i4[m + 16 * p]);
    __builtin_amdgcn_sched_barrier(0);

    // Residual add (a is L1/L2-hot broadcast) + partial sums.
    float s = 0.f, q = 0.f;
    #pragma unroll
    for (int p = 0; p < 16; ++p) {
        float4 av = a4[m + 16 * p];
        y[p].x += av.x;
        y[p].y += av.y;
        y[p].z += av.z;
        y[p].w += av.w;
        s += y[p].x + y[p].y + y[p].z + y[p].w;
        q += y[p].x * y[p].x + y[p].y * y[p].y
           + y[p].z * y[p].z + y[p].w * y[p].w;
    }

    // 4-stride butterfly within the 16-lane row group; every lane of the
    // group ends with the full row (s, q).
    #pragma unroll
    for (int off = 8; off; off >>= 1) {
        s += __shfl_xor(s, off, 64);
        q += __shfl_xor(q, off, 64);
    }
    const float mu   = s * (1.0f / E_DIM);
    const float rstd = rsqrtf(q * (1.0f / E_DIM) - mu * mu + 1e-5f);

    // Phase B: apply from registers; gamma/beta are L1-hot broadcasts.
    #pragma unroll
    for (int p = 0; p < 16; ++p) {
        float4 gv = g4[m + 16 * p];
        float4 bv = b4[m + 16 * p];
        nvf4 ov;
        ov.x = (y[p].x - mu) * rstd * gv.x + bv.x;
        ov.y = (y[p].y - mu) * rstd * gv.y + bv.y;
        ov.z = (y[p].z - mu) * rstd * gv.z + bv.z;
        ov.w = (y[p].w - mu) * rstd * gv.w + bv.w;
        __builtin_nontemporal_store(ov, &o4[m + 16 * p]);
    }
}

extern "C" void kernel_launch(void* const* d_in, const int* in_sizes, int n_in,
                              void* d_out, int out_size, void* d_ws, size_t ws_size,
                              hipStream_t stream) {
    // setup_inputs order:
    // 0 img_feat [B,S,E], 1 heat_feat [B,E], 2 W_img, 3 b_img, 4 W_heat, 5 b_heat,
    // 6 Wq, 7 bq, 8 Wk, 9 bk, 10 Wv, 11 bv, 12 Wo, 13 bo, 14 gamma, 15 beta
    const float* heat   = (const float*)d_in[1];
    const float* W_heat = (const float*)d_in[4];
    const float* b_heat = (const float*)d_in[5];
    const float* Wv     = (const float*)d_in[10];
    const float* bvv    = (const float*)d_in[11];
    const float* Wo     = (const float*)d_in[12];
    const float* bo     = (const float*)d_in[13];
    const float* img    = (const float*)d_in[0];
    const float* gamma  = (const float*)d_in[14];
    const float* beta   = (const float*)d_in[15];
    float* out = (float*)d_out;

    // Workspace: 3 fp32 [B,E] buffers = 384 KiB.
    float* ws = (float*)d_ws;
    float* tt = ws;                      // W_heat stage
    float* vv = ws + B_DIM * E_DIM;      // Wv stage
    float* aa = ws + 2 * B_DIM * E_DIM;  // Wo stage (attn_out rows)

    // 1024 blocks = 256 row-groups x 4 batch-quarters.
    gemv_xlds<<<1024, 256, 0, stream>>>(W_heat, b_heat, heat, tt);
    gemv_xlds<<<1024, 256, 0, stream>>>(Wv, bvv, tt, vv);
    gemv_xlds<<<1024, 256, 0, stream>>>(Wo, bo, vv, aa);

    // 2048 blocks x 256 thr; 16 rows/block (4 rows per wave, 16 lanes/row).
    resid_ln<<<(B_DIM * S_DIM) / 16, 256, 0, stream>>>(img, aa, gamma, beta, out);
}